// Round 18
// baseline (200.330 us; speedup 1.0000x reference)
//
#include <hip/hip_runtime.h>
#include <hip/hip_bf16.h>

// Temporal_Aggregation — MFMA bf16, fp32 I/O (MI355X gfx950). Round 27.
//
// r17 falsified the write-path theory (full-line stores, WRITE_SIZE exactly
// ideal, yet 61-63 µs > r12's 58.7). Surviving invariant across 5 variants:
// ~60 µs, ~2.4 TB/s, ALL pipes <12% busy = 2.7x the 22 µs BW floor. The one
// never-varied element: block-wide barriers phase-couple each block's memory
// and compute phases (duty cycle ~35% = 2.4/6.8).
//
// Round-27: ZERO barriers. Block = 2 rows; its 4 waves each own one 16-o
// N-tile and stage the SAME 2 rows into a wave-PRIVATE LDS region (4x
// redundant cvt/ds_write; global loads identical across waves -> L1-served).
// Same-wave LDS RAW ordered by lgkmcnt (compiler). Waves free-run: loads,
// K-loop, and stores of different waves/blocks naturally interleave.
// Per-wave chain halves: 18 MFMA (3 M-tiles x 6 ks), 12 f4 loads, 2 rows.
// Epilogue = r12 shuffle band-sum reduced to 3 M-tiles (masks: t0 at
// mt0/quad0 + mt1/quad2; t23 at mt1/quad1 + mt2/quad3). Partial-line
// stores proven equivalent (r17).
//
// Folded math (validated rounds 4-8):
//   Wbig[o][j=k*64+i] = sum_c Wlin[o][c]*Wconv[c][i][0][k]   (bf16 in ws)
//   z[t][o]  = sum_j Vp[t+(j>>6)][j&63] * Wbig[o][j]
//   out[t][o] = relu( z[t-1]+z[t]+z[t+1] (clipped) + m_t*biasC[o] + blin[o] )

typedef __attribute__((ext_vector_type(8))) short short8;
typedef __attribute__((ext_vector_type(8))) __bf16 bf16x8;
typedef __attribute__((ext_vector_type(4))) float f4;

#define ROWS_PB 2                      // rows per block (shared by 4 waves)
#define VP_STRIDE 72                   // 64 + 8 pad shorts
#define ROW_SHORTS (26 * VP_STRIDE)    // 1872 shorts per padded row
#define WREG_SHORTS (ROWS_PB * ROW_SHORTS)  // 3744 shorts = 7488 B per wave

__device__ __forceinline__ unsigned short f2bfu(float f) {
    return __bfloat16_as_ushort(__float2bfloat16(f));
}

// ---- Kernel 1: fold conv+linear weights -------------------------------------
// ws bytes: [0,24576) Wbig bf16[64][192]; [24576,24832) biasC f32[64];
//           [24832,25088) blinF f32[64]
__global__ void prep_kernel(const float* __restrict__ Wconv,
                            const float* __restrict__ bconv,
                            const float* __restrict__ Wlin,
                            const float* __restrict__ blin,
                            __hip_bfloat16* __restrict__ wbig,
                            float* __restrict__ biasC,
                            float* __restrict__ blinF) {
    __shared__ float Wl[4096];
    const int tid = threadIdx.x;
    for (int c = tid; c < 4096; c += 256) Wl[c] = Wlin[c];
    __syncthreads();
    int idx = blockIdx.x * 256 + tid;
    if (idx < 64 * 192) {
        int o = idx / 192;
        int j = idx - o * 192;
        int k = j >> 6;
        int i = j & 63;
        float acc = 0.0f;
        for (int c = 0; c < 64; ++c)
            acc += Wl[o * 64 + c] * Wconv[c * 192 + i * 3 + k];
        wbig[o * 192 + j] = __float2bfloat16(acc);
    } else if (idx < 64 * 192 + 64) {
        int o = idx - 64 * 192;
        float acc = 0.0f;
        for (int c = 0; c < 64; ++c)
            acc += Wl[o * 64 + c] * bconv[c];
        biasC[o] = acc;
    } else if (idx < 64 * 192 + 128) {
        int o = idx - (64 * 192 + 64);
        blinF[o] = blin[o];
    }
}

// ---- Kernel 2: barrier-free fused conv-GEMM + band sum + bias + relu --------
__global__ __launch_bounds__(256, 4) void fused_kernel(
    const float* __restrict__ value,
    const __hip_bfloat16* __restrict__ wbig,
    const float* __restrict__ biasC,
    const float* __restrict__ blinF,
    float* __restrict__ out) {
    // 4 wave-PRIVATE staging regions; no cross-wave sharing, no barriers.
    __shared__ __align__(16) short Vlds[4 * WREG_SHORTS];        // 29952 B

    const int tid = threadIdx.x;
    const int wave = tid >> 6;            // = o-tile index (16 columns)
    const int lane = tid & 63;
    const int lane15 = lane & 15;
    const int quad = lane >> 4;
    const long base_row = (long)blockIdx.x * ROWS_PB;

    short* const wbase = Vlds + wave * WREG_SHORTS;

    // ---- issue value loads first (HBM long pole); 2 rows, fully coalesced --
    f4 pre[12];
    const int tq = quad;                  // t mod 4 group
    const int d4 = lane15 << 2;           // float4 column
    {
        const float* vb = value + base_row * 1536 + tq * 64 + d4;
        #pragma unroll
        for (int rr = 0; rr < 2; ++rr)
            #pragma unroll
            for (int j = 0; j < 6; ++j)
                pre[rr * 6 + j] = *(const f4*)(vb + rr * 1536 + j * 256);
    }

    // ---- B fragments for this wave's o-tile (L2-hot after block 0) ----
    const short* wsrc = (const short*)wbig;
    const int k0 = quad * 8;
    bf16x8 breg[6];
    #pragma unroll
    for (int ks = 0; ks < 6; ++ks)
        breg[ks] = __builtin_bit_cast(bf16x8,
            *(const short8*)(wsrc + (wave * 16 + lane15) * 192 + ks * 32 + k0));

    const int o = wave * 16 + lane15;
    const float bc = biasC[o];
    const float bl = blinF[o];

    // ---- zero pad rows (t=-1 -> padded row 0, t=24 -> padded row 25) ----
    if (lane < 32) {
        int rr = (lane >> 4) & 1;
        int which = (lane >> 3) & 1;
        int d8 = (lane & 7) << 3;
        uint4 z; z.x = 0; z.y = 0; z.z = 0; z.w = 0;
        *(uint4*)(wbase + rr * ROW_SHORTS + which * (25 * VP_STRIDE) + d8) = z;
    }
    // ---- cvt + private ds_write (compiler orders via vmcnt/lgkmcnt) ----
    {
        short* lbase = wbase + (tq + 1) * VP_STRIDE + d4;
        #pragma unroll
        for (int rr = 0; rr < 2; ++rr)
            #pragma unroll
            for (int j = 0; j < 6; ++j) {
                f4 p = pre[rr * 6 + j];
                ushort4 u;
                u.x = f2bfu(p.x); u.y = f2bfu(p.y);
                u.z = f2bfu(p.z); u.w = f2bfu(p.w);
                *(ushort4*)(lbase + rr * ROW_SHORTS + j * (4 * VP_STRIDE)) = u;
            }
    }
    // NO __syncthreads anywhere.

    // ---- K-loop: 3 M-tiles (m=0..47 over 2 rows) x 6 ks, pure LDS+MFMA ----
    int aoff[3];
    #pragma unroll
    for (int mt = 0; mt < 3; ++mt) {
        int m = mt * 16 + lane15;          // m = rr*24 + s
        int rr = m / 24;
        int s = m - rr * 24;
        aoff[mt] = rr * ROW_SHORTS + s * VP_STRIDE;
    }
    f4 acc[3];
    #pragma unroll
    for (int mt = 0; mt < 3; ++mt) {
        f4 zz = {0.f, 0.f, 0.f, 0.f};
        acc[mt] = zz;
    }
    #pragma unroll
    for (int ks = 0; ks < 6; ++ks) {
        int k = ks * 32 + k0;
        int ka = ((k >> 6) * VP_STRIDE) + (k & 63);
        #pragma unroll
        for (int mt = 0; mt < 3; ++mt) {
            bf16x8 a = __builtin_bit_cast(bf16x8,
                *(const short8*)(wbase + aoff[mt] + ka));
            acc[mt] = __builtin_amdgcn_mfma_f32_16x16x32_bf16(
                a, breg[ks], acc[mt], 0, 0, 0);
        }
    }

    // ---- epilogue: wave-local shuffle band sum, bias, relu, store ----
    // C/D layout: col = lane&15, row16 = quad*4 + i  [m89]
    // m = mt*16 + quad*4 + i (0..47); out off = blockIdx*3072 + m*64 + o.
    // t0 at m=0 (mt0,q0) and m=24 (mt1,q2); t23 at m=23 (mt1,q1) and
    // m=47 (mt2,q3); all at i=0 / i=3 only (m === i mod 4).
    const float b3 = 3.0f * bc + bl;
    const float b2 = 2.0f * bc + bl;
    const int srcP = (lane + 48) & 63;    // receive from quad-1
    const int srcN = (lane + 16) & 63;    // receive from quad+1
    float* pbase = out + (long)blockIdx.x * 3072 + quad * 256 + o;
    #pragma unroll
    for (int mt = 0; mt < 3; ++mt) {
        const int mtp = (mt > 0) ? mt - 1 : 0;
        const int mtn = (mt < 2) ? mt + 1 : 2;
        float sendP = (quad == 3) ? acc[mtp][3] : acc[mt][3];
        float sendN = (quad == 0) ? acc[mtn][0] : acc[mt][0];
        float prev0 = __shfl(sendP, srcP, 64);
        float next3 = __shfl(sendN, srcN, 64);
        const bool t0  = (mt == 0) ? (quad == 0)
                       : ((mt == 1) ? (quad == 2) : false);
        const bool t23 = (mt == 2) ? (quad == 3)
                       : ((mt == 1) ? (quad == 1) : false);
        float s0 = acc[mt][0] + acc[mt][1] + (t0  ? b2 : (prev0 + b3));
        float s1 = acc[mt][0] + acc[mt][1] + acc[mt][2] + b3;
        float s2 = acc[mt][1] + acc[mt][2] + acc[mt][3] + b3;
        float s3 = acc[mt][2] + acc[mt][3] + (t23 ? b2 : (next3 + b3));
        float* p = pbase + mt * 1024;     // mt*16*64, compile-time
        p[0]   = fmaxf(s0, 0.0f);
        p[64]  = fmaxf(s1, 0.0f);
        p[128] = fmaxf(s2, 0.0f);
        p[192] = fmaxf(s3, 0.0f);
    }
}

extern "C" void kernel_launch(void* const* d_in, const int* in_sizes, int n_in,
                              void* d_out, int out_size, void* d_ws, size_t ws_size,
                              hipStream_t stream) {
    const float* value = (const float*)d_in[0];
    const float* Wconv = (const float*)d_in[1];
    const float* bconv = (const float*)d_in[2];
    const float* Wlin  = (const float*)d_in[3];
    const float* blin  = (const float*)d_in[4];
    float* out = (float*)d_out;

    __hip_bfloat16* wbig = (__hip_bfloat16*)d_ws;
    float* biasC = (float*)((char*)d_ws + 24576);
    float* blinF = (float*)((char*)d_ws + 24832);

    prep_kernel<<<49, 256, 0, stream>>>(Wconv, bconv, Wlin, blin, wbig, biasC, blinF);
    // 16384 rows / 2 per block = 8192 blocks, zero barriers
    fused_kernel<<<8192, 256, 0, stream>>>(value, wbig, biasC, blinF, out);
}